// Round 10
// baseline (654.794 us; speedup 1.0000x reference)
//
#include <hip/hip_runtime.h>
#include <stdint.h>

#define NG   64
#define NPG  4096
#define HD   256
#define NC0  256
#define NC1  64
#define KSPLIT 2

typedef __attribute__((ext_vector_type(8))) short bfx8;   // 8 bf16 (4 VGPRs)
typedef __attribute__((ext_vector_type(4))) float fx4;    // MFMA acc

__device__ __forceinline__ unsigned short f2bf(float f) {
  union { float f; unsigned int u; } v; v.f = f;
  return (unsigned short)((v.u + 0x7FFFu + ((v.u >> 16) & 1u)) >> 16);  // RNE
}
__device__ __forceinline__ unsigned int pack2(float a, float b) {
  return (unsigned int)f2bf(a) | ((unsigned int)f2bf(b) << 16);
}

// async global->LDS, 16B per lane; LDS dest = wave-uniform base + lane*16
#define ASYNC_COPY16(gptr, lptr) \
  __builtin_amdgcn_global_load_lds((const __attribute__((address_space(1))) unsigned int*)(gptr), \
                                   (__attribute__((address_space(3))) unsigned int*)(lptr), 16, 0, 0)

// ---------------- W0 -> W0F: MFMA B-fragment order, bf16 (unchanged) ----------------
__global__ __launch_bounds__(256) void k_w0f(const float* __restrict__ W0,
                                             unsigned short* __restrict__ W0F) {
  int gid = blockIdx.x * 256 + threadIdx.x;   // 8192 granules
  int l15 = gid & 15;
  int q   = (gid >> 4) & 3;
  int ks  = (gid >> 6) & 1;
  int kc  = (gid >> 7) & 3;
  int cblk = gid >> 9;
  int c = cblk * 16 + l15;
  int kb = kc * 64 + ks * 32 + q * 8;
  unsigned int u[4];
  #pragma unroll
  for (int j = 0; j < 8; j += 2)
    u[j >> 1] = pack2(W0[(size_t)(kb + j) * 256 + c], W0[(size_t)(kb + j + 1) * 256 + c]);
  *(float4*)(W0F + (size_t)gid * 8) = *(float4*)u;
}

// ---------------- K1: softmax(x@W0+b0) -> A0T chunked; also emits xT chunked ----------------
// Round-4 body + 2-DEEP x prefetch: chunks kc+1 (va[]) and kc+2 (vb[]) in flight in
// registers simultaneously (1-deep staging left loads outstanding only ~25% of each phase
// -> 2.25 TB/s; 2-deep doubles the duty cycle). All va/vb indices are literal constants
// in unrolled code -> registers (rule #20). +32 VGPR: ~156 unified, under the (256,3)
// cap of 170 -> no spill expected. SPILL ALARM: VGPR_Count <= 64 => revert.
// launch_bounds LAW: (256,3)->76 ok; (256,4)->64 spill; (256,5)->48 heavy spill.
#define XLOAD(dst, ck) do { \
    const float4* _s = (const float4*)(xbase + (size_t)snode * HD + (ck) * 64 + sseg); \
    dst[0] = _s[0]; dst[1] = _s[1]; dst[2] = _s[2]; dst[3] = _s[3]; } while (0)
#define XWRITE(src, buf) do { \
    float4 pv[2]; unsigned int* pu = (unsigned int*)pv; \
    pu[0] = pack2(src[0].x, src[0].y); pu[1] = pack2(src[0].z, src[0].w); \
    pu[2] = pack2(src[1].x, src[1].y); pu[3] = pack2(src[1].z, src[1].w); \
    pu[4] = pack2(src[2].x, src[2].y); pu[5] = pack2(src[2].z, src[2].w); \
    pu[6] = pack2(src[3].x, src[3].y); pu[7] = pack2(src[3].z, src[3].w); \
    unsigned short* drow = &lds_u[(buf) * 4096 + (snode << 6)]; \
    *(float4*)(drow + (((sg0    ) ^ ssw) << 3)) = pv[0]; \
    *(float4*)(drow + (((sg0 + 1) ^ ssw) << 3)) = pv[1]; } while (0)

__global__ __launch_bounds__(256, 3) void k_assign0(
    const float* __restrict__ x, const unsigned short* __restrict__ W0F,
    const float* __restrict__ b0, unsigned short* __restrict__ A0T,
    unsigned short* __restrict__ xT, int g0) {
  __shared__ unsigned short lds_u[9216];   // xs: [2][64][64] (16KB) | at: [128][72] (18432B)
  __shared__ float red[64 * 4];

  int gl = blockIdx.x >> 6, nt = blockIdx.x & 63;
  int tid = threadIdx.x;
  int wn = tid >> 6, lane = tid & 63;
  int l15 = lane & 15, q = lane >> 4;

  fx4 acc[4][4];
  #pragma unroll
  for (int i = 0; i < 4; ++i)
    #pragma unroll
    for (int j = 0; j < 4; ++j) acc[i][j] = fx4{0.f, 0.f, 0.f, 0.f};

  const float* xbase = x + ((size_t)(g0 + gl) * NPG + (size_t)nt * 64) * HD;
  int snode = tid >> 2, sseg = (tid & 3) * 16;   // 64 rows x 4 segs of 16 floats
  int sg0  = (tid & 3) * 2;                      // even granule index
  int ssw  = (snode ^ (snode >> 4)) & 7;         // stage swizzle

  bfx8 bvc[4], bvn[4];
  #pragma unroll
  for (int ni = 0; ni < 4; ++ni)                 // B-frag group 0
    bvc[ni] = *(const bfx8*)(W0F + ((size_t)(((wn * 4 + ni) * 8 + 0) * 64 + lane)) * 8);

  float4 va[4], vb[4];
  // prologue: chunk0 -> va -> LDS buf0; chunk1 -> vb (in flight); chunk2 -> va (in flight)
  XLOAD(va, 0);
  XLOAD(vb, 1);
  XWRITE(va, 0);
  XLOAD(va, 2);
  __syncthreads();

  #pragma unroll
  for (int kc = 0; kc < 4; ++kc) {
    const unsigned short* xb = &lds_u[(kc & 1) * 4096];
    #pragma unroll
    for (int ks = 0; ks < 2; ++ks) {
      int g8 = kc * 2 + ks;
      if (g8 < 7) {   // B-frag double-buffer (L2-resident W0F)
        #pragma unroll
        for (int ni = 0; ni < 4; ++ni)
          bvn[ni] = *(const bfx8*)(W0F + ((size_t)(((wn * 4 + ni) * 8 + g8 + 1) * 64 + lane)) * 8);
      }
      bfx8 af[4];
      #pragma unroll
      for (int mi = 0; mi < 4; ++mi) {
        int row = mi * 16 + l15;
        int slot = (ks * 4 + q) ^ ((row ^ (row >> 4)) & 7);
        af[mi] = *(const bfx8*)&xb[(row << 6) + (slot << 3)];
      }
      #pragma unroll
      for (int ni = 0; ni < 4; ++ni)
        #pragma unroll
        for (int mi = 0; mi < 4; ++mi)
          acc[mi][ni] = __builtin_amdgcn_mfma_f32_16x16x32_bf16(af[mi], bvc[ni], acc[mi][ni], 0, 0, 0);
      if (g8 < 7) {
        #pragma unroll
        for (int ni = 0; ni < 4; ++ni) bvc[ni] = bvn[ni];
      }
    }
    // emit xT chunk rows [kc*64 .. +64)
    {
      int hl = tid >> 2, s4 = tid & 3, sgn = s4 * 16;
      int g = hl >> 3, off = hl & 7;
      unsigned int u[8];
      #pragma unroll
      for (int i = 0; i < 16; i += 2) {
        int n0 = sgn + i, n1 = n0 + 1;
        unsigned short a = xb[(n0 << 6) + ((g ^ ((n0 ^ (n0 >> 4)) & 7)) << 3) + off];
        unsigned short b = xb[(n1 << 6) + ((g ^ ((n1 ^ (n1 >> 4)) & 7)) << 3) + off];
        u[i >> 1] = (unsigned int)a | ((unsigned int)b << 16);
      }
      float4* dst = (float4*)(xT + ((size_t)(gl * 64 + nt) * HD + kc * 64 + hl) * 64 + sgn);
      dst[0] = *(float4*)&u[0];
      dst[1] = *(float4*)&u[4];
    }
    // rolling 2-deep prefetch: write the chunk due next, keep 2 in flight
    if (kc == 0) { XWRITE(vb, 1); XLOAD(vb, 3); }   // vb: chunk1 -> LDS; load chunk3
    else if (kc == 1) { XWRITE(va, 0); }            // va: chunk2 -> LDS buf0
    else if (kc == 2) { XWRITE(vb, 1); }            // vb: chunk3 -> LDS buf1
    __syncthreads();
  }

  // ---- epilogue: bias + softmax over 256 clusters per node-row ----
  float bv4[4];
  #pragma unroll
  for (int ni = 0; ni < 4; ++ni) bv4[ni] = b0[wn * 64 + ni * 16 + l15];
  #pragma unroll
  for (int mi = 0; mi < 4; ++mi)
    #pragma unroll
    for (int ni = 0; ni < 4; ++ni)
      #pragma unroll
      for (int r = 0; r < 4; ++r) acc[mi][ni][r] += bv4[ni];

  float mrow[4][4];
  #pragma unroll
  for (int mi = 0; mi < 4; ++mi)
    #pragma unroll
    for (int r = 0; r < 4; ++r) {
      float m = fmaxf(fmaxf(acc[mi][0][r], acc[mi][1][r]), fmaxf(acc[mi][2][r], acc[mi][3][r]));
      #pragma unroll
      for (int off = 1; off < 16; off <<= 1) m = fmaxf(m, __shfl_xor(m, off));
      mrow[mi][r] = m;
    }
  if (l15 == 0) {
    #pragma unroll
    for (int mi = 0; mi < 4; ++mi)
      #pragma unroll
      for (int r = 0; r < 4; ++r)
        red[(mi * 16 + q * 4 + r) * 4 + wn] = mrow[mi][r];
  }
  __syncthreads();
  #pragma unroll
  for (int mi = 0; mi < 4; ++mi)
    #pragma unroll
    for (int r = 0; r < 4; ++r) {
      float4 rv = *(const float4*)&red[(mi * 16 + q * 4 + r) * 4];
      mrow[mi][r] = fmaxf(fmaxf(rv.x, rv.y), fmaxf(rv.z, rv.w));
    }
  __syncthreads();
  float srow[4][4];
  #pragma unroll
  for (int mi = 0; mi < 4; ++mi)
    #pragma unroll
    for (int r = 0; r < 4; ++r) {
      float s = 0.f;
      #pragma unroll
      for (int ni = 0; ni < 4; ++ni) {
        float e = __expf(acc[mi][ni][r] - mrow[mi][r]);
        acc[mi][ni][r] = e; s += e;
      }
      #pragma unroll
      for (int off = 1; off < 16; off <<= 1) s += __shfl_xor(s, off);
      srow[mi][r] = s;
    }
  if (l15 == 0) {
    #pragma unroll
    for (int mi = 0; mi < 4; ++mi)
      #pragma unroll
      for (int r = 0; r < 4; ++r)
        red[(mi * 16 + q * 4 + r) * 4 + wn] = srow[mi][r];
  }
  __syncthreads();
  #pragma unroll
  for (int mi = 0; mi < 4; ++mi)
    #pragma unroll
    for (int r = 0; r < 4; ++r) {
      float4 rv = *(const float4*)&red[(mi * 16 + q * 4 + r) * 4];
      float inv = 1.f / (rv.x + rv.y + rv.z + rv.w);
      #pragma unroll
      for (int ni = 0; ni < 4; ++ni) acc[mi][ni][r] *= inv;
    }
  __syncthreads();   // xs dead; reuse as 'at'

  // ---- transposed store: A0T chunk [256 c][64 n], two 128-cluster phases via LDS ----
  unsigned short* at = lds_u;                 // [128 c][72 n]
  unsigned short* A0Tg = A0T + (size_t)(gl * 64 + nt) * NC0 * 64;
  #pragma unroll
  for (int p = 0; p < 2; ++p) {
    if ((wn >> 1) == p) {
      int cb = (wn & 1) * 64;
      #pragma unroll
      for (int mi = 0; mi < 4; ++mi) {
        int ncol = mi * 16 + q * 4;
        #pragma unroll
        for (int ni = 0; ni < 4; ++ni) {
          int cl = cb + ni * 16 + l15;
          uint2 w;
          w.x = pack2(acc[mi][ni][0], acc[mi][ni][1]);
          w.y = pack2(acc[mi][ni][2], acc[mi][ni][3]);
          *(uint2*)(at + cl * 72 + ncol) = w;
        }
      }
    }
    __syncthreads();
    {
      int row = tid >> 1, sg2 = (tid & 1) * 32;
      const float4* s4p = (const float4*)(at + row * 72 + sg2);
      float4 a = s4p[0], b = s4p[1], c = s4p[2], d = s4p[3];
      float4* d4 = (float4*)(A0Tg + (size_t)(p * 128 + row) * 64 + sg2);
      d4[0] = a; d4[1] = b; d4[2] = c; d4[3] = d;
    }
    __syncthreads();
  }
}

// ---------------- K2: f0 += A0T . xT (atomic accumulate, both kidx halves) ----------------
// Counted-vmcnt pipeline + KSPLIT=2 + 512 blocks (2/CU) kept from round 8. NEW: output via
// atomicAdd into f0 directly (f0 pre-zeroed) -> kills the 16MB partial write, the 48MB
// k_f0sum pass, and one launch. 8.4M f32 atomics total, L2-absorbed.
__global__ __launch_bounds__(512, 2) void k_pool0(
    const unsigned short* __restrict__ A0T, const unsigned short* __restrict__ xT,
    float* __restrict__ f0, int g0) {
  __shared__ unsigned short a_s[2][128 * 64];
  __shared__ unsigned short b_s[2][128 * 64];
  int bid = blockIdx.x;
  int gl, mt, nt, kidx;
  if (gridDim.x == 512) {           // G=64 path: pair p = (kidx<<6)|gl, p&7 == XCD
    int xcd = bid & 7, s = bid >> 3;            // s 0..63
    int p = xcd + 8 * (s >> 2);                 // 0..127
    gl = p & 63; kidx = p >> 6;
    int j = s & 3; mt = j >> 1; nt = j & 1;
  } else {
    nt = bid & 1; mt = (bid >> 1) & 1; kidx = (bid >> 2) & 1; gl = bid >> 3;
  }

  int tid = threadIdx.x;
  int wave = tid >> 6, lane = tid & 63;
  int wm = wave >> 2, wn = wave & 3;
  int l15 = lane & 15, q = lane >> 4;

  const int TPK = (NPG / 64) / KSPLIT;          // 32 chunks per block
  const unsigned short* abase = A0T + (size_t)gl * 64 * NC0 * 64 + (size_t)kidx * TPK * 16384 + (size_t)mt * 128 * 64;
  const unsigned short* bbase = xT  + (size_t)gl * 64 * HD  * 64 + (size_t)kidx * TPK * 16384 + (size_t)nt * 128 * 64;

  fx4 acc[4][2];
  #pragma unroll
  for (int i = 0; i < 4; ++i)
    #pragma unroll
    for (int j = 0; j < 2; ++j) acc[i][j] = fx4{0.f, 0.f, 0.f, 0.f};

  int srow = lane >> 3;                 // 0..7 row within 8-row group
  int sg   = (lane & 7) ^ srow;         // swizzled 16B granule
  size_t soff = (size_t)srow * 64 + (size_t)sg * 8;   // shorts (row stride 64)

  // prologue: issue chunks 0 and 1
  #pragma unroll
  for (int c = 0; c < 2; ++c) {
    size_t co = (size_t)c * 16384;
    #pragma unroll
    for (int i = 0; i < 2; ++i) {
      int r0 = wave * 16 + i * 8;
      ASYNC_COPY16(abase + co + (size_t)r0 * 64 + soff, &a_s[c][r0 * 64]);
      ASYNC_COPY16(bbase + co + (size_t)r0 * 64 + soff, &b_s[c][r0 * 64]);
    }
  }

  for (int t = 0; t < TPK; ++t) {
    int buf = t & 1;
    if (t < TPK - 1) asm volatile("s_waitcnt vmcnt(4)" ::: "memory");
    else             asm volatile("s_waitcnt vmcnt(0)" ::: "memory");
    __builtin_amdgcn_s_barrier();       // all waves' chunk-t data visible in LDS

    bfx8 af[2][4], bf[2][2];
    #pragma unroll
    for (int ks = 0; ks < 2; ++ks) {
      int gx = ((ks * 4 + q) ^ (l15 & 7)) << 3;
      #pragma unroll
      for (int mi = 0; mi < 4; ++mi)
        af[ks][mi] = *(const bfx8*)&a_s[buf][(wm * 64 + mi * 16 + l15) * 64 + gx];
      #pragma unroll
      for (int ni = 0; ni < 2; ++ni)
        bf[ks][ni] = *(const bfx8*)&b_s[buf][(wn * 32 + ni * 16 + l15) * 64 + gx];
    }
    asm volatile("s_waitcnt lgkmcnt(0)" ::: "memory");
    __builtin_amdgcn_s_barrier();       // all waves done reading buf

    if (t + 2 < TPK) {                  // re-stage this buffer with chunk t+2
      size_t co = (size_t)(t + 2) * 16384;
      #pragma unroll
      for (int i = 0; i < 2; ++i) {
        int r0 = wave * 16 + i * 8;
        ASYNC_COPY16(abase + co + (size_t)r0 * 64 + soff, &a_s[buf][r0 * 64]);
        ASYNC_COPY16(bbase + co + (size_t)r0 * 64 + soff, &b_s[buf][r0 * 64]);
      }
    }
    #pragma unroll
    for (int ks = 0; ks < 2; ++ks)
      #pragma unroll
      for (int ni = 0; ni < 2; ++ni)
        #pragma unroll
        for (int mi = 0; mi < 4; ++mi)
          acc[mi][ni] = __builtin_amdgcn_mfma_f32_16x16x32_bf16(af[ks][mi], bf[ks][ni], acc[mi][ni], 0, 0, 0);
  }

  float* dst = f0 + ((size_t)(g0 + gl) * NC0 + (size_t)mt * 128) * HD + (size_t)nt * 128;
  #pragma unroll
  for (int mi = 0; mi < 4; ++mi)
    #pragma unroll
    for (int ni = 0; ni < 2; ++ni) {
      int c = wm * 64 + mi * 16 + q * 4;
      int h = wn * 32 + ni * 16 + l15;
      #pragma unroll
      for (int r = 0; r < 4; ++r)
        atomicAdd(&dst[(size_t)(c + r) * HD + h], acc[mi][ni][r]);
    }
}

// ---------------- K3: A1 = softmax(f0 @ W1 + b1); W1 staged in LDS (unchanged) ----------------
__global__ __launch_bounds__(256) void k_assign1(
    const float* __restrict__ f0, const float* __restrict__ W1,
    const float* __restrict__ b1, float* __restrict__ A1) {
  __shared__ float w1s[256 * 64];   // 64 KB
  int tid = threadIdx.x;
  #pragma unroll
  for (int i = 0; i < 16; ++i) {
    int off = i * 1024 + tid * 4;
    *(float4*)(w1s + off) = *(const float4*)(W1 + off);
  }
  __syncthreads();
  int lane = tid & 63;
  int rbase = blockIdx.x * 32 + (tid >> 6) * 8;
  float bias = b1[lane];
  for (int rr = 0; rr < 8; ++rr) {
    int row = rbase + rr;
    const float* fr = f0 + (size_t)row * 256;
    float acc = bias;
    for (int k = 0; k < 256; k += 4) {
      float4 fv = *(const float4*)(fr + k);
      acc += fv.x * w1s[(k    ) * 64 + lane];
      acc += fv.y * w1s[(k + 1) * 64 + lane];
      acc += fv.z * w1s[(k + 2) * 64 + lane];
      acc += fv.w * w1s[(k + 3) * 64 + lane];
    }
    float m = acc;
    #pragma unroll
    for (int off = 1; off < 64; off <<= 1) m = fmaxf(m, __shfl_xor(m, off));
    float e = __expf(acc - m);
    float s = e;
    #pragma unroll
    for (int off = 1; off < 64; off <<= 1) s += __shfl_xor(s, off);
    A1[(size_t)row * 64 + lane] = e / s;
  }
}

// ---------------- K4: f1 = A1^T-weighted pool of f0 (round-7 form) ----------------
__global__ __launch_bounds__(1024) void k_pool1(
    const float* __restrict__ A1, const float* __restrict__ f0, float* __restrict__ f1) {
  __shared__ float part[3 * 256 * 16];   // 48 KB
  int b = blockIdx.x >> 2, cg = blockIdx.x & 3;
  int tid = threadIdx.x;
  int c0g = tid >> 8;                    // 0..3
  int h = tid & 255;
  const float* a1p = A1 + (size_t)b * NC0 * NC1 + cg * 16;
  const float* f0p = f0 + (size_t)b * NC0 * HD + h;
  float acc[16];
  #pragma unroll
  for (int j = 0; j < 16; ++j) acc[j] = 0.f;
  for (int c0 = c0g * 64; c0 < c0g * 64 + 64; ++c0) {
    float fv = f0p[(size_t)c0 * 256];
    #pragma unroll
    for (int j = 0; j < 16; ++j) acc[j] += a1p[c0 * 64 + j] * fv;
  }
  if (c0g > 0) {
    float* d = &part[((c0g - 1) * 256 + h) * 16];
    #pragma unroll
    for (int j = 0; j < 16; ++j) d[j] = acc[j];
  }
  __syncthreads();
  if (c0g == 0) {
    #pragma unroll
    for (int g = 0; g < 3; ++g) {
      const float* s = &part[(g * 256 + h) * 16];
      #pragma unroll
      for (int j = 0; j < 16; ++j) acc[j] += s[j];
    }
    float* d = f1 + (size_t)b * 16384 + (size_t)(cg * 16) * 256 + h;
    #pragma unroll
    for (int j = 0; j < 16; ++j) d[(size_t)j * 256] = acc[j];
  }
}

// ---------------- K5a: ot += f1 . Wf slice (round-7 form) ----------------
__global__ __launch_bounds__(512) void k_final_partial(
    const float* __restrict__ f1, const float* __restrict__ Wf, float* __restrict__ ot) {
  __shared__ float f1s[32 * 256];   // 32 KB: f1[32 graphs][k-slice]
  int ks = blockIdx.x >> 2;
  int ht = (blockIdx.x >> 1) & 1;
  int bh = blockIdx.x & 1;
  int tid = threadIdx.x;
  #pragma unroll
  for (int i = 0; i < 4; ++i) {
    int idx = i * 512 + tid;          // 2048 float4s = 32 rows x 64
    int bb = idx >> 6, c4 = idx & 63;
    *(float4*)(f1s + bb * 256 + c4 * 4) =
        *(const float4*)(f1 + (size_t)(bh * 32 + bb) * 16384 + (size_t)ks * 256 + c4 * 4);
  }
  __syncthreads();
  int h = ht * 128 + (tid & 127);
  int b0 = (tid >> 7) * 8;            // 8 graphs within the half
  const float* wp = Wf + (size_t)ks * 256 * 256 + h;
  float acc[8];
  #pragma unroll
  for (int j = 0; j < 8; ++j) acc[j] = 0.f;
  for (int k = 0; k < 256; k += 4) {
    float w0 = wp[(size_t)(k    ) * 256];
    float w1 = wp[(size_t)(k + 1) * 256];
    float w2 = wp[(size_t)(k + 2) * 256];
    float w3 = wp[(size_t)(k + 3) * 256];
    #pragma unroll
    for (int j = 0; j < 8; ++j) {
      float4 fv = *(const float4*)(f1s + (b0 + j) * 256 + k);
      acc[j] += fv.x * w0 + fv.y * w1 + fv.z * w2 + fv.w * w3;
    }
  }
  #pragma unroll
  for (int j = 0; j < 8; ++j) atomicAdd(&ot[(bh * 32 + b0 + j) * 256 + h], acc[j]);
}

// ---------------- K5b: out = relu(ot + bf) (unchanged) ----------------
__global__ __launch_bounds__(256) void k_final_out(
    const float* __restrict__ ot, const float* __restrict__ bfv, float* __restrict__ out) {
  int i = blockIdx.x * 256 + threadIdx.x;
  float v = ot[i] + bfv[i & 255];
  out[i] = v > 0.f ? v : 0.f;
}

extern "C" void kernel_launch(void* const* d_in, const int* in_sizes, int n_in,
                              void* d_out, int out_size, void* d_ws, size_t ws_size,
                              hipStream_t stream) {
  const float* x   = (const float*)d_in[0];
  const float* W0  = (const float*)d_in[3];
  const float* b0  = (const float*)d_in[4];
  const float* W1  = (const float*)d_in[5];
  const float* b1  = (const float*)d_in[6];
  const float* Wf  = (const float*)d_in[7];
  const float* bfv = (const float*)d_in[8];
  float* out = (float*)d_out;
  char* ws = (char*)d_ws;

  // layout: f0 16 MB @0 (atomic-accumulated); ot @32M; W0F @32M+64K;
  // chunk region @32M+192K: xT (G*2MB) + A0T (G*2MB). f1 aliases xT, A1 aliases A0T.
  float* f0  = (float*)ws;
  float* ot  = (float*)(ws + ((size_t)32 << 20));
  unsigned short* W0F = (unsigned short*)(ws + ((size_t)32 << 20) + 65536);
  size_t chunk_off = ((size_t)32 << 20) + 65536 + 131072;
  size_t per_graph = (size_t)4 * HD * NPG;   // xT(2MB)+A0T(2MB)
  size_t avail = ws_size > chunk_off ? ws_size - chunk_off : 0;
  int G = (int)(avail / per_graph);
  if (G > 64) G = 64;   // G=64: pool0 gets its full 512-block grid (2 blocks/CU)
  if (G < 1) G = 1;
  unsigned short* xT  = (unsigned short*)(ws + chunk_off);
  unsigned short* A0T = xT + (size_t)G * HD * NPG;
  float* f1 = (float*)xT;    // 16 MB, used after k_pool0 (needs G>=8)
  float* A1 = (float*)A0T;   // 4 MB, used after k_pool0

  hipMemsetAsync(ot, 0, 65536, stream);
  hipMemsetAsync(f0, 0, (size_t)NG * NC0 * HD * 4, stream);   // 16 MB, pool0 accumulates
  k_w0f<<<32, 256, 0, stream>>>(W0, W0F);

  for (int g0 = 0; g0 < NG; g0 += G) {
    int gc = (NG - g0 < G) ? (NG - g0) : G;
    k_assign0<<<gc * 64, 256, 0, stream>>>(x, W0F, b0, A0T, xT, g0);
    k_pool0<<<gc * 4 * KSPLIT, 512, 0, stream>>>(A0T, xT, f0, g0);
  }
  k_assign1<<<512, 256, 0, stream>>>(f0, W1, b1, A1);
  k_pool1<<<256, 1024, 0, stream>>>(A1, f0, f1);
  k_final_partial<<<256, 512, 0, stream>>>(f1, Wf, ot);
  k_final_out<<<64, 256, 0, stream>>>(ot, bfv, out);
}

// Round 11
// 649.942 us; speedup vs baseline: 1.0075x; 1.0075x over previous
//
#include <hip/hip_runtime.h>
#include <stdint.h>

#define NG   64
#define NPG  4096
#define HD   256
#define NC0  256
#define NC1  64
#define KSPLIT 4

typedef __attribute__((ext_vector_type(8))) short bfx8;   // 8 bf16 (4 VGPRs)
typedef __attribute__((ext_vector_type(4))) float fx4;    // MFMA acc

__device__ __forceinline__ unsigned short f2bf(float f) {
  union { float f; unsigned int u; } v; v.f = f;
  return (unsigned short)((v.u + 0x7FFFu + ((v.u >> 16) & 1u)) >> 16);  // RNE
}
__device__ __forceinline__ unsigned int pack2(float a, float b) {
  return (unsigned int)f2bf(a) | ((unsigned int)f2bf(b) << 16);
}

// async global->LDS, 16B per lane; LDS dest = wave-uniform base + lane*16
#define ASYNC_COPY16(gptr, lptr) \
  __builtin_amdgcn_global_load_lds((const __attribute__((address_space(1))) unsigned int*)(gptr), \
                                   (__attribute__((address_space(3))) unsigned int*)(lptr), 16, 0, 0)

// ---------------- W0 -> W0F: MFMA B-fragment order, bf16 (unchanged) ----------------
__global__ __launch_bounds__(256) void k_w0f(const float* __restrict__ W0,
                                             unsigned short* __restrict__ W0F) {
  int gid = blockIdx.x * 256 + threadIdx.x;   // 8192 granules
  int l15 = gid & 15;
  int q   = (gid >> 4) & 3;
  int ks  = (gid >> 6) & 1;
  int kc  = (gid >> 7) & 3;
  int cblk = gid >> 9;
  int c = cblk * 16 + l15;
  int kb = kc * 64 + ks * 32 + q * 8;
  unsigned int u[4];
  #pragma unroll
  for (int j = 0; j < 8; j += 2)
    u[j >> 1] = pack2(W0[(size_t)(kb + j) * 256 + c], W0[(size_t)(kb + j + 1) * 256 + c]);
  *(float4*)(W0F + (size_t)gid * 8) = *(float4*)u;
}

// ---------------- K1: softmax(x@W0+b0) -> A0T chunked; also emits xT chunked ----------------
// VERBATIM round-8 proven kernel (181us, 262MB W / 134MB F, VGPR 76, no spill).
// REGISTER WALL (4 data points): (256,3)+1-deep = 76 VGPR, 181us (floor);
// (256,4)/(256,5) = spill catastrophe; (256,3)+2-deep prefetch = 84 VGPR mild spill,
// 196us (+57MB traffic). This body has ~0 spare regs at 3 blocks/CU. DO NOT deepen.
__global__ __launch_bounds__(256, 3) void k_assign0(
    const float* __restrict__ x, const unsigned short* __restrict__ W0F,
    const float* __restrict__ b0, unsigned short* __restrict__ A0T,
    unsigned short* __restrict__ xT, int g0) {
  __shared__ unsigned short lds_u[9216];   // xs: [2][64][64] (16KB) | at: [128][72] (18432B)
  __shared__ float red[64 * 4];

  int gl = blockIdx.x >> 6, nt = blockIdx.x & 63;
  int tid = threadIdx.x;
  int wn = tid >> 6, lane = tid & 63;
  int l15 = lane & 15, q = lane >> 4;

  fx4 acc[4][4];
  #pragma unroll
  for (int i = 0; i < 4; ++i)
    #pragma unroll
    for (int j = 0; j < 4; ++j) acc[i][j] = fx4{0.f, 0.f, 0.f, 0.f};

  const float* xbase = x + ((size_t)(g0 + gl) * NPG + (size_t)nt * 64) * HD;
  int snode = tid >> 2, sseg = (tid & 3) * 16;   // 64 rows x 4 segs of 16 floats
  int sg0  = (tid & 3) * 2;                      // even granule index
  int ssw  = (snode ^ (snode >> 4)) & 7;         // stage swizzle

  bfx8 bvc[4], bvn[4];
  #pragma unroll
  for (int ni = 0; ni < 4; ++ni)                 // B-frag group 0
    bvc[ni] = *(const bfx8*)(W0F + ((size_t)(((wn * 4 + ni) * 8 + 0) * 64 + lane)) * 8);

  // prologue: stage chunk 0 into buf 0
  {
    const float4* src = (const float4*)(xbase + (size_t)snode * HD + sseg);
    float4 v0 = src[0], v1 = src[1], v2 = src[2], v3 = src[3];
    float4 pv[2]; unsigned int* pu = (unsigned int*)pv;
    pu[0] = pack2(v0.x, v0.y); pu[1] = pack2(v0.z, v0.w);
    pu[2] = pack2(v1.x, v1.y); pu[3] = pack2(v1.z, v1.w);
    pu[4] = pack2(v2.x, v2.y); pu[5] = pack2(v2.z, v2.w);
    pu[6] = pack2(v3.x, v3.y); pu[7] = pack2(v3.z, v3.w);
    unsigned short* drow = &lds_u[snode << 6];
    *(float4*)(drow + (((sg0    ) ^ ssw) << 3)) = pv[0];
    *(float4*)(drow + (((sg0 + 1) ^ ssw) << 3)) = pv[1];
  }
  __syncthreads();

  for (int kc = 0; kc < 4; ++kc) {
    const unsigned short* xb = &lds_u[(kc & 1) * 4096];
    float4 v0, v1, v2, v3;
    if (kc < 3) {   // T14: issue next-chunk global loads EARLY
      const float4* src = (const float4*)(xbase + (size_t)snode * HD + (kc + 1) * 64 + sseg);
      v0 = src[0]; v1 = src[1]; v2 = src[2]; v3 = src[3];
    }
    #pragma unroll
    for (int ks = 0; ks < 2; ++ks) {
      int g8 = kc * 2 + ks;
      if (g8 < 7) {   // B-frag double-buffer (L2-resident W0F)
        #pragma unroll
        for (int ni = 0; ni < 4; ++ni)
          bvn[ni] = *(const bfx8*)(W0F + ((size_t)(((wn * 4 + ni) * 8 + g8 + 1) * 64 + lane)) * 8);
      }
      bfx8 af[4];
      #pragma unroll
      for (int mi = 0; mi < 4; ++mi) {
        int row = mi * 16 + l15;
        int slot = (ks * 4 + q) ^ ((row ^ (row >> 4)) & 7);
        af[mi] = *(const bfx8*)&xb[(row << 6) + (slot << 3)];
      }
      #pragma unroll
      for (int ni = 0; ni < 4; ++ni)
        #pragma unroll
        for (int mi = 0; mi < 4; ++mi)
          acc[mi][ni] = __builtin_amdgcn_mfma_f32_16x16x32_bf16(af[mi], bvc[ni], acc[mi][ni], 0, 0, 0);
      if (g8 < 7) {
        #pragma unroll
        for (int ni = 0; ni < 4; ++ni) bvc[ni] = bvn[ni];
      }
    }
    // emit xT chunk rows [kc*64 .. +64)
    {
      int hl = tid >> 2, s4 = tid & 3, sgn = s4 * 16;
      int g = hl >> 3, off = hl & 7;
      unsigned int u[8];
      #pragma unroll
      for (int i = 0; i < 16; i += 2) {
        int n0 = sgn + i, n1 = n0 + 1;
        unsigned short a = xb[(n0 << 6) + ((g ^ ((n0 ^ (n0 >> 4)) & 7)) << 3) + off];
        unsigned short b = xb[(n1 << 6) + ((g ^ ((n1 ^ (n1 >> 4)) & 7)) << 3) + off];
        u[i >> 1] = (unsigned int)a | ((unsigned int)b << 16);
      }
      float4* dst = (float4*)(xT + ((size_t)(gl * 64 + nt) * HD + kc * 64 + hl) * 64 + sgn);
      dst[0] = *(float4*)&u[0];
      dst[1] = *(float4*)&u[4];
    }
    if (kc < 3) {   // T14: pack + LDS-write LATE
      float4 pv[2]; unsigned int* pu = (unsigned int*)pv;
      pu[0] = pack2(v0.x, v0.y); pu[1] = pack2(v0.z, v0.w);
      pu[2] = pack2(v1.x, v1.y); pu[3] = pack2(v1.z, v1.w);
      pu[4] = pack2(v2.x, v2.y); pu[5] = pack2(v2.z, v2.w);
      pu[6] = pack2(v3.x, v3.y); pu[7] = pack2(v3.z, v3.w);
      unsigned short* drow = &lds_u[(((kc & 1) ^ 1) * 4096) + (snode << 6)];
      *(float4*)(drow + (((sg0    ) ^ ssw) << 3)) = pv[0];
      *(float4*)(drow + (((sg0 + 1) ^ ssw) << 3)) = pv[1];
    }
    __syncthreads();
  }

  // ---- epilogue: bias + softmax over 256 clusters per node-row ----
  float bv4[4];
  #pragma unroll
  for (int ni = 0; ni < 4; ++ni) bv4[ni] = b0[wn * 64 + ni * 16 + l15];
  #pragma unroll
  for (int mi = 0; mi < 4; ++mi)
    #pragma unroll
    for (int ni = 0; ni < 4; ++ni)
      #pragma unroll
      for (int r = 0; r < 4; ++r) acc[mi][ni][r] += bv4[ni];

  float mrow[4][4];
  #pragma unroll
  for (int mi = 0; mi < 4; ++mi)
    #pragma unroll
    for (int r = 0; r < 4; ++r) {
      float m = fmaxf(fmaxf(acc[mi][0][r], acc[mi][1][r]), fmaxf(acc[mi][2][r], acc[mi][3][r]));
      #pragma unroll
      for (int off = 1; off < 16; off <<= 1) m = fmaxf(m, __shfl_xor(m, off));
      mrow[mi][r] = m;
    }
  if (l15 == 0) {
    #pragma unroll
    for (int mi = 0; mi < 4; ++mi)
      #pragma unroll
      for (int r = 0; r < 4; ++r)
        red[(mi * 16 + q * 4 + r) * 4 + wn] = mrow[mi][r];
  }
  __syncthreads();
  #pragma unroll
  for (int mi = 0; mi < 4; ++mi)
    #pragma unroll
    for (int r = 0; r < 4; ++r) {
      float4 rv = *(const float4*)&red[(mi * 16 + q * 4 + r) * 4];
      mrow[mi][r] = fmaxf(fmaxf(rv.x, rv.y), fmaxf(rv.z, rv.w));
    }
  __syncthreads();
  float srow[4][4];
  #pragma unroll
  for (int mi = 0; mi < 4; ++mi)
    #pragma unroll
    for (int r = 0; r < 4; ++r) {
      float s = 0.f;
      #pragma unroll
      for (int ni = 0; ni < 4; ++ni) {
        float e = __expf(acc[mi][ni][r] - mrow[mi][r]);
        acc[mi][ni][r] = e; s += e;
      }
      #pragma unroll
      for (int off = 1; off < 16; off <<= 1) s += __shfl_xor(s, off);
      srow[mi][r] = s;
    }
  if (l15 == 0) {
    #pragma unroll
    for (int mi = 0; mi < 4; ++mi)
      #pragma unroll
      for (int r = 0; r < 4; ++r)
        red[(mi * 16 + q * 4 + r) * 4 + wn] = srow[mi][r];
  }
  __syncthreads();
  #pragma unroll
  for (int mi = 0; mi < 4; ++mi)
    #pragma unroll
    for (int r = 0; r < 4; ++r) {
      float4 rv = *(const float4*)&red[(mi * 16 + q * 4 + r) * 4];
      float inv = 1.f / (rv.x + rv.y + rv.z + rv.w);
      #pragma unroll
      for (int ni = 0; ni < 4; ++ni) acc[mi][ni][r] *= inv;
    }
  __syncthreads();   // xs dead; reuse as 'at'

  // ---- transposed store: A0T chunk [256 c][64 n], two 128-cluster phases via LDS ----
  unsigned short* at = lds_u;                 // [128 c][72 n]
  unsigned short* A0Tg = A0T + (size_t)(gl * 64 + nt) * NC0 * 64;
  #pragma unroll
  for (int p = 0; p < 2; ++p) {
    if ((wn >> 1) == p) {
      int cb = (wn & 1) * 64;
      #pragma unroll
      for (int mi = 0; mi < 4; ++mi) {
        int ncol = mi * 16 + q * 4;
        #pragma unroll
        for (int ni = 0; ni < 4; ++ni) {
          int cl = cb + ni * 16 + l15;
          uint2 w;
          w.x = pack2(acc[mi][ni][0], acc[mi][ni][1]);
          w.y = pack2(acc[mi][ni][2], acc[mi][ni][3]);
          *(uint2*)(at + cl * 72 + ncol) = w;
        }
      }
    }
    __syncthreads();
    {
      int row = tid >> 1, sg2 = (tid & 1) * 32;
      const float4* s4p = (const float4*)(at + row * 72 + sg2);
      float4 a = s4p[0], b = s4p[1], c = s4p[2], d = s4p[3];
      float4* d4 = (float4*)(A0Tg + (size_t)(p * 128 + row) * 64 + sg2);
      d4[0] = a; d4[1] = b; d4[2] = c; d4[3] = d;
    }
    __syncthreads();
  }
}

// ---------------- K2: f0p[kidx] partial = A0T . xT over a quarter of the K range ----------------
// Counted-vmcnt pipeline kept. NEW: KSPLIT=4 -> grid 1024 -> ~3-4 blocks/CU residency
// (launch_bounds(512,2) unchanged: VGPR cap 128 >> the ~76 this body needs, zero spill
// risk). If this third occupancy poke is also neutral, pool0 is L2/HBM-bound at ~150us
// and the structure is at its practical floor.
__global__ __launch_bounds__(512, 2) void k_pool0(
    const unsigned short* __restrict__ A0T, const unsigned short* __restrict__ xT,
    float* __restrict__ f0p, int g0) {
  __shared__ unsigned short a_s[2][128 * 64];
  __shared__ unsigned short b_s[2][128 * 64];
  int bid = blockIdx.x;
  int gl, mt, nt, kidx;
  if (gridDim.x == 1024) {          // G=64 path: p = (kidx<<6)|gl; p&7 spread per XCD
    int xcd = bid & 7, s = bid >> 3;            // s 0..127
    int p = xcd + 8 * (s >> 2);                 // 0..255
    gl = p & 63; kidx = p >> 6;
    int j = s & 3; mt = j >> 1; nt = j & 1;
  } else {
    nt = bid & 1; mt = (bid >> 1) & 1; kidx = (bid >> 2) & 3; gl = bid >> 4;
  }

  int tid = threadIdx.x;
  int wave = tid >> 6, lane = tid & 63;
  int wm = wave >> 2, wn = wave & 3;
  int l15 = lane & 15, q = lane >> 4;

  const int TPK = (NPG / 64) / KSPLIT;          // 16 chunks per block
  const unsigned short* abase = A0T + (size_t)gl * 64 * NC0 * 64 + (size_t)kidx * TPK * 16384 + (size_t)mt * 128 * 64;
  const unsigned short* bbase = xT  + (size_t)gl * 64 * HD  * 64 + (size_t)kidx * TPK * 16384 + (size_t)nt * 128 * 64;

  fx4 acc[4][2];
  #pragma unroll
  for (int i = 0; i < 4; ++i)
    #pragma unroll
    for (int j = 0; j < 2; ++j) acc[i][j] = fx4{0.f, 0.f, 0.f, 0.f};

  int srow = lane >> 3;                 // 0..7 row within 8-row group
  int sg   = (lane & 7) ^ srow;         // swizzled 16B granule
  size_t soff = (size_t)srow * 64 + (size_t)sg * 8;   // shorts (row stride 64)

  // prologue: issue chunks 0 and 1
  #pragma unroll
  for (int c = 0; c < 2; ++c) {
    size_t co = (size_t)c * 16384;
    #pragma unroll
    for (int i = 0; i < 2; ++i) {
      int r0 = wave * 16 + i * 8;
      ASYNC_COPY16(abase + co + (size_t)r0 * 64 + soff, &a_s[c][r0 * 64]);
      ASYNC_COPY16(bbase + co + (size_t)r0 * 64 + soff, &b_s[c][r0 * 64]);
    }
  }

  for (int t = 0; t < TPK; ++t) {
    int buf = t & 1;
    if (t < TPK - 1) asm volatile("s_waitcnt vmcnt(4)" ::: "memory");
    else             asm volatile("s_waitcnt vmcnt(0)" ::: "memory");
    __builtin_amdgcn_s_barrier();       // all waves' chunk-t data visible in LDS

    bfx8 af[2][4], bf[2][2];
    #pragma unroll
    for (int ks = 0; ks < 2; ++ks) {
      int gx = ((ks * 4 + q) ^ (l15 & 7)) << 3;
      #pragma unroll
      for (int mi = 0; mi < 4; ++mi)
        af[ks][mi] = *(const bfx8*)&a_s[buf][(wm * 64 + mi * 16 + l15) * 64 + gx];
      #pragma unroll
      for (int ni = 0; ni < 2; ++ni)
        bf[ks][ni] = *(const bfx8*)&b_s[buf][(wn * 32 + ni * 16 + l15) * 64 + gx];
    }
    asm volatile("s_waitcnt lgkmcnt(0)" ::: "memory");
    __builtin_amdgcn_s_barrier();       // all waves done reading buf

    if (t + 2 < TPK) {                  // re-stage this buffer with chunk t+2
      size_t co = (size_t)(t + 2) * 16384;
      #pragma unroll
      for (int i = 0; i < 2; ++i) {
        int r0 = wave * 16 + i * 8;
        ASYNC_COPY16(abase + co + (size_t)r0 * 64 + soff, &a_s[buf][r0 * 64]);
        ASYNC_COPY16(bbase + co + (size_t)r0 * 64 + soff, &b_s[buf][r0 * 64]);
      }
    }
    #pragma unroll
    for (int ks = 0; ks < 2; ++ks)
      #pragma unroll
      for (int ni = 0; ni < 2; ++ni)
        #pragma unroll
        for (int mi = 0; mi < 4; ++mi)
          acc[mi][ni] = __builtin_amdgcn_mfma_f32_16x16x32_bf16(af[ks][mi], bf[ks][ni], acc[mi][ni], 0, 0, 0);
  }

  float* dst = f0p + (size_t)kidx * NG * NC0 * HD
             + ((size_t)(g0 + gl) * NC0 + (size_t)mt * 128) * HD + (size_t)nt * 128;
  #pragma unroll
  for (int mi = 0; mi < 4; ++mi)
    #pragma unroll
    for (int ni = 0; ni < 2; ++ni) {
      int c = wm * 64 + mi * 16 + q * 4;
      int h = wn * 32 + ni * 16 + l15;
      #pragma unroll
      for (int r = 0; r < 4; ++r)
        dst[(size_t)(c + r) * HD + h] = acc[mi][ni][r];
    }
}

// ---------------- f0 = f0p0 + f0p1 + f0p2 + f0p3 (in place: f0 == f0p0) ----------------
__global__ __launch_bounds__(256) void k_f0sum(float* __restrict__ f0) {
  size_t i = ((size_t)blockIdx.x * 256 + threadIdx.x) * 4;
  const size_t S = (size_t)NG * NC0 * HD;
  float4 a = *(const float4*)(f0 + i);
  float4 b = *(const float4*)(f0 + S + i);
  float4 c = *(const float4*)(f0 + 2 * S + i);
  float4 d = *(const float4*)(f0 + 3 * S + i);
  a.x += b.x + c.x + d.x; a.y += b.y + c.y + d.y;
  a.z += b.z + c.z + d.z; a.w += b.w + c.w + d.w;
  *(float4*)(f0 + i) = a;
}

// ---------------- K3: A1 = softmax(f0 @ W1 + b1); W1 staged in LDS (unchanged) ----------------
__global__ __launch_bounds__(256) void k_assign1(
    const float* __restrict__ f0, const float* __restrict__ W1,
    const float* __restrict__ b1, float* __restrict__ A1) {
  __shared__ float w1s[256 * 64];   // 64 KB
  int tid = threadIdx.x;
  #pragma unroll
  for (int i = 0; i < 16; ++i) {
    int off = i * 1024 + tid * 4;
    *(float4*)(w1s + off) = *(const float4*)(W1 + off);
  }
  __syncthreads();
  int lane = tid & 63;
  int rbase = blockIdx.x * 32 + (tid >> 6) * 8;
  float bias = b1[lane];
  for (int rr = 0; rr < 8; ++rr) {
    int row = rbase + rr;
    const float* fr = f0 + (size_t)row * 256;
    float acc = bias;
    for (int k = 0; k < 256; k += 4) {
      float4 fv = *(const float4*)(fr + k);
      acc += fv.x * w1s[(k    ) * 64 + lane];
      acc += fv.y * w1s[(k + 1) * 64 + lane];
      acc += fv.z * w1s[(k + 2) * 64 + lane];
      acc += fv.w * w1s[(k + 3) * 64 + lane];
    }
    float m = acc;
    #pragma unroll
    for (int off = 1; off < 64; off <<= 1) m = fmaxf(m, __shfl_xor(m, off));
    float e = __expf(acc - m);
    float s = e;
    #pragma unroll
    for (int off = 1; off < 64; off <<= 1) s += __shfl_xor(s, off);
    A1[(size_t)row * 64 + lane] = e / s;
  }
}

// ---------------- K4: f1 = A1^T-weighted pool of f0 (round-7 form) ----------------
__global__ __launch_bounds__(1024) void k_pool1(
    const float* __restrict__ A1, const float* __restrict__ f0, float* __restrict__ f1) {
  __shared__ float part[3 * 256 * 16];   // 48 KB
  int b = blockIdx.x >> 2, cg = blockIdx.x & 3;
  int tid = threadIdx.x;
  int c0g = tid >> 8;                    // 0..3
  int h = tid & 255;
  const float* a1p = A1 + (size_t)b * NC0 * NC1 + cg * 16;
  const float* f0p = f0 + (size_t)b * NC0 * HD + h;
  float acc[16];
  #pragma unroll
  for (int j = 0; j < 16; ++j) acc[j] = 0.f;
  for (int c0 = c0g * 64; c0 < c0g * 64 + 64; ++c0) {
    float fv = f0p[(size_t)c0 * 256];
    #pragma unroll
    for (int j = 0; j < 16; ++j) acc[j] += a1p[c0 * 64 + j] * fv;
  }
  if (c0g > 0) {
    float* d = &part[((c0g - 1) * 256 + h) * 16];
    #pragma unroll
    for (int j = 0; j < 16; ++j) d[j] = acc[j];
  }
  __syncthreads();
  if (c0g == 0) {
    #pragma unroll
    for (int g = 0; g < 3; ++g) {
      const float* s = &part[(g * 256 + h) * 16];
      #pragma unroll
      for (int j = 0; j < 16; ++j) acc[j] += s[j];
    }
    float* d = f1 + (size_t)b * 16384 + (size_t)(cg * 16) * 256 + h;
    #pragma unroll
    for (int j = 0; j < 16; ++j) d[(size_t)j * 256] = acc[j];
  }
}

// ---------------- K5a: ot += f1 . Wf slice (round-7 form) ----------------
__global__ __launch_bounds__(512) void k_final_partial(
    const float* __restrict__ f1, const float* __restrict__ Wf, float* __restrict__ ot) {
  __shared__ float f1s[32 * 256];   // 32 KB: f1[32 graphs][k-slice]
  int ks = blockIdx.x >> 2;
  int ht = (blockIdx.x >> 1) & 1;
  int bh = blockIdx.x & 1;
  int tid = threadIdx.x;
  #pragma unroll
  for (int i = 0; i < 4; ++i) {
    int idx = i * 512 + tid;          // 2048 float4s = 32 rows x 64
    int bb = idx >> 6, c4 = idx & 63;
    *(float4*)(f1s + bb * 256 + c4 * 4) =
        *(const float4*)(f1 + (size_t)(bh * 32 + bb) * 16384 + (size_t)ks * 256 + c4 * 4);
  }
  __syncthreads();
  int h = ht * 128 + (tid & 127);
  int b0 = (tid >> 7) * 8;            // 8 graphs within the half
  const float* wp = Wf + (size_t)ks * 256 * 256 + h;
  float acc[8];
  #pragma unroll
  for (int j = 0; j < 8; ++j) acc[j] = 0.f;
  for (int k = 0; k < 256; k += 4) {
    float w0 = wp[(size_t)(k    ) * 256];
    float w1 = wp[(size_t)(k + 1) * 256];
    float w2 = wp[(size_t)(k + 2) * 256];
    float w3 = wp[(size_t)(k + 3) * 256];
    #pragma unroll
    for (int j = 0; j < 8; ++j) {
      float4 fv = *(const float4*)(f1s + (b0 + j) * 256 + k);
      acc[j] += fv.x * w0 + fv.y * w1 + fv.z * w2 + fv.w * w3;
    }
  }
  #pragma unroll
  for (int j = 0; j < 8; ++j) atomicAdd(&ot[(bh * 32 + b0 + j) * 256 + h], acc[j]);
}

// ---------------- K5b: out = relu(ot + bf) (unchanged) ----------------
__global__ __launch_bounds__(256) void k_final_out(
    const float* __restrict__ ot, const float* __restrict__ bfv, float* __restrict__ out) {
  int i = blockIdx.x * 256 + threadIdx.x;
  float v = ot[i] + bfv[i & 255];
  out[i] = v > 0.f ? v : 0.f;
}

extern "C" void kernel_launch(void* const* d_in, const int* in_sizes, int n_in,
                              void* d_out, int out_size, void* d_ws, size_t ws_size,
                              hipStream_t stream) {
  const float* x   = (const float*)d_in[0];
  const float* W0  = (const float*)d_in[3];
  const float* b0  = (const float*)d_in[4];
  const float* W1  = (const float*)d_in[5];
  const float* b1  = (const float*)d_in[6];
  const float* Wf  = (const float*)d_in[7];
  const float* bfv = (const float*)d_in[8];
  float* out = (float*)d_out;
  char* ws = (char*)d_ws;

  // layout: f0p 4x16 MB @0 (partial0 doubles as f0); ot @64M; W0F @64M+64K;
  // chunk region @64M+192K: xT (G*2MB) + A0T (G*2MB). f1 aliases xT, A1 aliases A0T.
  float* f0p = (float*)ws;
  float* f0  = f0p;
  float* ot  = (float*)(ws + ((size_t)64 << 20));
  unsigned short* W0F = (unsigned short*)(ws + ((size_t)64 << 20) + 65536);
  size_t chunk_off = ((size_t)64 << 20) + 65536 + 131072;
  size_t per_graph = (size_t)4 * HD * NPG;   // xT(2MB)+A0T(2MB)
  size_t avail = ws_size > chunk_off ? ws_size - chunk_off : 0;
  int G = (int)(avail / per_graph);
  if (G > 64) G = 64;   // G=64: pool0 gets its full 1024-block grid
  if (G < 1) G = 1;
  unsigned short* xT  = (unsigned short*)(ws + chunk_off);
  unsigned short* A0T = xT + (size_t)G * HD * NPG;
  float* f1 = (float*)xT;    // 16 MB, used after k_pool0 (needs G>=8)
  float* A1 = (float*)A0T;   // 4 MB, used after k_pool0

  hipMemsetAsync(ot, 0, 65536, stream);
  k_w0f<<<32, 256, 0, stream>>>(W0, W0F);

  for (int g0 = 0; g0 < NG; g0 += G) {
    int gc = (NG - g0 < G) ? (NG - g0) : G;
    k_assign0<<<gc * 64, 256, 0, stream>>>(x, W0F, b0, A0T, xT, g0);
    k_pool0<<<gc * 4 * KSPLIT, 512, 0, stream>>>(A0T, xT, f0p, g0);
  }
  k_f0sum<<<4096, 256, 0, stream>>>(f0);
  k_assign1<<<512, 256, 0, stream>>>(f0, W1, b1, A1);
  k_pool1<<<256, 1024, 0, stream>>>(A1, f0, f1);
  k_final_partial<<<256, 512, 0, stream>>>(f1, Wf, ot);
  k_final_out<<<64, 256, 0, stream>>>(ot, bfv, out);
}

// Round 12
// 635.947 us; speedup vs baseline: 1.0296x; 1.0220x over previous
//
#include <hip/hip_runtime.h>
#include <stdint.h>

#define NG   64
#define NPG  4096
#define HD   256
#define NC0  256
#define NC1  64
#define KSPLIT 2

typedef __attribute__((ext_vector_type(8))) short bfx8;   // 8 bf16 (4 VGPRs)
typedef __attribute__((ext_vector_type(4))) float fx4;    // MFMA acc

__device__ __forceinline__ unsigned short f2bf(float f) {
  union { float f; unsigned int u; } v; v.f = f;
  return (unsigned short)((v.u + 0x7FFFu + ((v.u >> 16) & 1u)) >> 16);  // RNE
}
__device__ __forceinline__ unsigned int pack2(float a, float b) {
  return (unsigned int)f2bf(a) | ((unsigned int)f2bf(b) << 16);
}

// async global->LDS, 16B per lane; LDS dest = wave-uniform base + lane*16
#define ASYNC_COPY16(gptr, lptr) \
  __builtin_amdgcn_global_load_lds((const __attribute__((address_space(1))) unsigned int*)(gptr), \
                                   (__attribute__((address_space(3))) unsigned int*)(lptr), 16, 0, 0)

// ---------------- W0 -> W0F: MFMA B-fragment order, bf16 ----------------
__global__ __launch_bounds__(256) void k_w0f(const float* __restrict__ W0,
                                             unsigned short* __restrict__ W0F) {
  int gid = blockIdx.x * 256 + threadIdx.x;   // 8192 granules
  int l15 = gid & 15;
  int q   = (gid >> 4) & 3;
  int ks  = (gid >> 6) & 1;
  int kc  = (gid >> 7) & 3;
  int cblk = gid >> 9;
  int c = cblk * 16 + l15;
  int kb = kc * 64 + ks * 32 + q * 8;
  unsigned int u[4];
  #pragma unroll
  for (int j = 0; j < 8; j += 2)
    u[j >> 1] = pack2(W0[(size_t)(kb + j) * 256 + c], W0[(size_t)(kb + j + 1) * 256 + c]);
  *(float4*)(W0F + (size_t)gid * 8) = *(float4*)u;
}

// ---------------- K1: softmax(x@W0+b0) -> A0T chunked; also emits xT chunked ----------------
// TERMINAL CONFIG (round-8 body, best verified: 181us, 262MB W / 134MB F, VGPR 76).
// REGISTER WALL (4 data points): (256,3)+1-deep prefetch = 76 VGPR, no spill = the ONLY
// working point. (256,4)->64 VGPR spill (+390MB HBM); (256,5)->48 heavy spill (+1.6GB);
// (256,3)+2-deep prefetch -> 84 VGPR mild spill (+57MB, 196us). Traffic is at the logical
// floor; bandwidth (~2.25 TB/s) is capped by latency-hiding which is capped by registers.
__global__ __launch_bounds__(256, 3) void k_assign0(
    const float* __restrict__ x, const unsigned short* __restrict__ W0F,
    const float* __restrict__ b0, unsigned short* __restrict__ A0T,
    unsigned short* __restrict__ xT, int g0) {
  __shared__ unsigned short lds_u[9216];   // xs: [2][64][64] (16KB) | at: [128][72] (18432B)
  __shared__ float red[64 * 4];

  int gl = blockIdx.x >> 6, nt = blockIdx.x & 63;
  int tid = threadIdx.x;
  int wn = tid >> 6, lane = tid & 63;
  int l15 = lane & 15, q = lane >> 4;

  fx4 acc[4][4];
  #pragma unroll
  for (int i = 0; i < 4; ++i)
    #pragma unroll
    for (int j = 0; j < 4; ++j) acc[i][j] = fx4{0.f, 0.f, 0.f, 0.f};

  const float* xbase = x + ((size_t)(g0 + gl) * NPG + (size_t)nt * 64) * HD;
  int snode = tid >> 2, sseg = (tid & 3) * 16;   // 64 rows x 4 segs of 16 floats
  int sg0  = (tid & 3) * 2;                      // even granule index
  int ssw  = (snode ^ (snode >> 4)) & 7;         // stage swizzle

  bfx8 bvc[4], bvn[4];
  #pragma unroll
  for (int ni = 0; ni < 4; ++ni)                 // B-frag group 0
    bvc[ni] = *(const bfx8*)(W0F + ((size_t)(((wn * 4 + ni) * 8 + 0) * 64 + lane)) * 8);

  // prologue: stage chunk 0 into buf 0
  {
    const float4* src = (const float4*)(xbase + (size_t)snode * HD + sseg);
    float4 v0 = src[0], v1 = src[1], v2 = src[2], v3 = src[3];
    float4 pv[2]; unsigned int* pu = (unsigned int*)pv;
    pu[0] = pack2(v0.x, v0.y); pu[1] = pack2(v0.z, v0.w);
    pu[2] = pack2(v1.x, v1.y); pu[3] = pack2(v1.z, v1.w);
    pu[4] = pack2(v2.x, v2.y); pu[5] = pack2(v2.z, v2.w);
    pu[6] = pack2(v3.x, v3.y); pu[7] = pack2(v3.z, v3.w);
    unsigned short* drow = &lds_u[snode << 6];
    *(float4*)(drow + (((sg0    ) ^ ssw) << 3)) = pv[0];
    *(float4*)(drow + (((sg0 + 1) ^ ssw) << 3)) = pv[1];
  }
  __syncthreads();

  for (int kc = 0; kc < 4; ++kc) {
    const unsigned short* xb = &lds_u[(kc & 1) * 4096];
    float4 v0, v1, v2, v3;
    if (kc < 3) {   // T14: issue next-chunk global loads EARLY
      const float4* src = (const float4*)(xbase + (size_t)snode * HD + (kc + 1) * 64 + sseg);
      v0 = src[0]; v1 = src[1]; v2 = src[2]; v3 = src[3];
    }
    #pragma unroll
    for (int ks = 0; ks < 2; ++ks) {
      int g8 = kc * 2 + ks;
      if (g8 < 7) {   // B-frag double-buffer (L2-resident W0F)
        #pragma unroll
        for (int ni = 0; ni < 4; ++ni)
          bvn[ni] = *(const bfx8*)(W0F + ((size_t)(((wn * 4 + ni) * 8 + g8 + 1) * 64 + lane)) * 8);
      }
      bfx8 af[4];
      #pragma unroll
      for (int mi = 0; mi < 4; ++mi) {
        int row = mi * 16 + l15;
        int slot = (ks * 4 + q) ^ ((row ^ (row >> 4)) & 7);
        af[mi] = *(const bfx8*)&xb[(row << 6) + (slot << 3)];
      }
      #pragma unroll
      for (int ni = 0; ni < 4; ++ni)
        #pragma unroll
        for (int mi = 0; mi < 4; ++mi)
          acc[mi][ni] = __builtin_amdgcn_mfma_f32_16x16x32_bf16(af[mi], bvc[ni], acc[mi][ni], 0, 0, 0);
      if (g8 < 7) {
        #pragma unroll
        for (int ni = 0; ni < 4; ++ni) bvc[ni] = bvn[ni];
      }
    }
    // emit xT chunk rows [kc*64 .. +64)
    {
      int hl = tid >> 2, s4 = tid & 3, sgn = s4 * 16;
      int g = hl >> 3, off = hl & 7;
      unsigned int u[8];
      #pragma unroll
      for (int i = 0; i < 16; i += 2) {
        int n0 = sgn + i, n1 = n0 + 1;
        unsigned short a = xb[(n0 << 6) + ((g ^ ((n0 ^ (n0 >> 4)) & 7)) << 3) + off];
        unsigned short b = xb[(n1 << 6) + ((g ^ ((n1 ^ (n1 >> 4)) & 7)) << 3) + off];
        u[i >> 1] = (unsigned int)a | ((unsigned int)b << 16);
      }
      float4* dst = (float4*)(xT + ((size_t)(gl * 64 + nt) * HD + kc * 64 + hl) * 64 + sgn);
      dst[0] = *(float4*)&u[0];
      dst[1] = *(float4*)&u[4];
    }
    if (kc < 3) {   // T14: pack + LDS-write LATE
      float4 pv[2]; unsigned int* pu = (unsigned int*)pv;
      pu[0] = pack2(v0.x, v0.y); pu[1] = pack2(v0.z, v0.w);
      pu[2] = pack2(v1.x, v1.y); pu[3] = pack2(v1.z, v1.w);
      pu[4] = pack2(v2.x, v2.y); pu[5] = pack2(v2.z, v2.w);
      pu[6] = pack2(v3.x, v3.y); pu[7] = pack2(v3.z, v3.w);
      unsigned short* drow = &lds_u[(((kc & 1) ^ 1) * 4096) + (snode << 6)];
      *(float4*)(drow + (((sg0    ) ^ ssw) << 3)) = pv[0];
      *(float4*)(drow + (((sg0 + 1) ^ ssw) << 3)) = pv[1];
    }
    __syncthreads();
  }

  // ---- epilogue: bias + softmax over 256 clusters per node-row ----
  float bv4[4];
  #pragma unroll
  for (int ni = 0; ni < 4; ++ni) bv4[ni] = b0[wn * 64 + ni * 16 + l15];
  #pragma unroll
  for (int mi = 0; mi < 4; ++mi)
    #pragma unroll
    for (int ni = 0; ni < 4; ++ni)
      #pragma unroll
      for (int r = 0; r < 4; ++r) acc[mi][ni][r] += bv4[ni];

  float mrow[4][4];
  #pragma unroll
  for (int mi = 0; mi < 4; ++mi)
    #pragma unroll
    for (int r = 0; r < 4; ++r) {
      float m = fmaxf(fmaxf(acc[mi][0][r], acc[mi][1][r]), fmaxf(acc[mi][2][r], acc[mi][3][r]));
      #pragma unroll
      for (int off = 1; off < 16; off <<= 1) m = fmaxf(m, __shfl_xor(m, off));
      mrow[mi][r] = m;
    }
  if (l15 == 0) {
    #pragma unroll
    for (int mi = 0; mi < 4; ++mi)
      #pragma unroll
      for (int r = 0; r < 4; ++r)
        red[(mi * 16 + q * 4 + r) * 4 + wn] = mrow[mi][r];
  }
  __syncthreads();
  #pragma unroll
  for (int mi = 0; mi < 4; ++mi)
    #pragma unroll
    for (int r = 0; r < 4; ++r) {
      float4 rv = *(const float4*)&red[(mi * 16 + q * 4 + r) * 4];
      mrow[mi][r] = fmaxf(fmaxf(rv.x, rv.y), fmaxf(rv.z, rv.w));
    }
  __syncthreads();
  float srow[4][4];
  #pragma unroll
  for (int mi = 0; mi < 4; ++mi)
    #pragma unroll
    for (int r = 0; r < 4; ++r) {
      float s = 0.f;
      #pragma unroll
      for (int ni = 0; ni < 4; ++ni) {
        float e = __expf(acc[mi][ni][r] - mrow[mi][r]);
        acc[mi][ni][r] = e; s += e;
      }
      #pragma unroll
      for (int off = 1; off < 16; off <<= 1) s += __shfl_xor(s, off);
      srow[mi][r] = s;
    }
  if (l15 == 0) {
    #pragma unroll
    for (int mi = 0; mi < 4; ++mi)
      #pragma unroll
      for (int r = 0; r < 4; ++r)
        red[(mi * 16 + q * 4 + r) * 4 + wn] = srow[mi][r];
  }
  __syncthreads();
  #pragma unroll
  for (int mi = 0; mi < 4; ++mi)
    #pragma unroll
    for (int r = 0; r < 4; ++r) {
      float4 rv = *(const float4*)&red[(mi * 16 + q * 4 + r) * 4];
      float inv = 1.f / (rv.x + rv.y + rv.z + rv.w);
      #pragma unroll
      for (int ni = 0; ni < 4; ++ni) acc[mi][ni][r] *= inv;
    }
  __syncthreads();   // xs dead; reuse as 'at'

  // ---- transposed store: A0T chunk [256 c][64 n], two 128-cluster phases via LDS ----
  unsigned short* at = lds_u;                 // [128 c][72 n]
  unsigned short* A0Tg = A0T + (size_t)(gl * 64 + nt) * NC0 * 64;
  #pragma unroll
  for (int p = 0; p < 2; ++p) {
    if ((wn >> 1) == p) {
      int cb = (wn & 1) * 64;
      #pragma unroll
      for (int mi = 0; mi < 4; ++mi) {
        int ncol = mi * 16 + q * 4;
        #pragma unroll
        for (int ni = 0; ni < 4; ++ni) {
          int cl = cb + ni * 16 + l15;
          uint2 w;
          w.x = pack2(acc[mi][ni][0], acc[mi][ni][1]);
          w.y = pack2(acc[mi][ni][2], acc[mi][ni][3]);
          *(uint2*)(at + cl * 72 + ncol) = w;
        }
      }
    }
    __syncthreads();
    {
      int row = tid >> 1, sg2 = (tid & 1) * 32;
      const float4* s4p = (const float4*)(at + row * 72 + sg2);
      float4 a = s4p[0], b = s4p[1], c = s4p[2], d = s4p[3];
      float4* d4 = (float4*)(A0Tg + (size_t)(p * 128 + row) * 64 + sg2);
      d4[0] = a; d4[1] = b; d4[2] = c; d4[3] = d;
    }
    __syncthreads();
  }
}

// ---------------- K2: f0p[kidx] partial = A0T . xT over half the K range ----------------
// TERMINAL CONFIG (round-8): counted-vmcnt pipeline (vmcnt(4) mid-loop, never 0),
// KSPLIT=2, 512 blocks = 2/CU, XCD affinity. Five restructures (sync-dbuf, 1/2/4
// blocks/CU, KSPLIT 1/2/4) all within noise -> L2/HBM-bound at ~150us for its 536MB
// logical stream; insensitive to scheduling.
__global__ __launch_bounds__(512, 2) void k_pool0(
    const unsigned short* __restrict__ A0T, const unsigned short* __restrict__ xT,
    float* __restrict__ f0p, int g0) {
  __shared__ unsigned short a_s[2][128 * 64];
  __shared__ unsigned short b_s[2][128 * 64];
  int bid = blockIdx.x;
  int gl, mt, nt, kidx;
  if (gridDim.x == 512) {           // G=64 path: pair p = (kidx<<6)|gl, p&7 == XCD
    int xcd = bid & 7, s = bid >> 3;            // s 0..63
    int p = xcd + 8 * (s >> 2);                 // 0..127
    gl = p & 63; kidx = p >> 6;
    int j = s & 3; mt = j >> 1; nt = j & 1;
  } else {
    nt = bid & 1; mt = (bid >> 1) & 1; kidx = (bid >> 2) & 1; gl = bid >> 3;
  }

  int tid = threadIdx.x;
  int wave = tid >> 6, lane = tid & 63;
  int wm = wave >> 2, wn = wave & 3;
  int l15 = lane & 15, q = lane >> 4;

  const int TPK = (NPG / 64) / KSPLIT;          // 32 chunks per block
  const unsigned short* abase = A0T + (size_t)gl * 64 * NC0 * 64 + (size_t)kidx * TPK * 16384 + (size_t)mt * 128 * 64;
  const unsigned short* bbase = xT  + (size_t)gl * 64 * HD  * 64 + (size_t)kidx * TPK * 16384 + (size_t)nt * 128 * 64;

  fx4 acc[4][2];
  #pragma unroll
  for (int i = 0; i < 4; ++i)
    #pragma unroll
    for (int j = 0; j < 2; ++j) acc[i][j] = fx4{0.f, 0.f, 0.f, 0.f};

  int srow = lane >> 3;                 // 0..7 row within 8-row group
  int sg   = (lane & 7) ^ srow;         // swizzled 16B granule
  size_t soff = (size_t)srow * 64 + (size_t)sg * 8;   // shorts (row stride 64)

  // prologue: issue chunks 0 and 1
  #pragma unroll
  for (int c = 0; c < 2; ++c) {
    size_t co = (size_t)c * 16384;
    #pragma unroll
    for (int i = 0; i < 2; ++i) {
      int r0 = wave * 16 + i * 8;
      ASYNC_COPY16(abase + co + (size_t)r0 * 64 + soff, &a_s[c][r0 * 64]);
      ASYNC_COPY16(bbase + co + (size_t)r0 * 64 + soff, &b_s[c][r0 * 64]);
    }
  }

  for (int t = 0; t < TPK; ++t) {
    int buf = t & 1;
    if (t < TPK - 1) asm volatile("s_waitcnt vmcnt(4)" ::: "memory");
    else             asm volatile("s_waitcnt vmcnt(0)" ::: "memory");
    __builtin_amdgcn_s_barrier();       // all waves' chunk-t data visible in LDS

    bfx8 af[2][4], bf[2][2];
    #pragma unroll
    for (int ks = 0; ks < 2; ++ks) {
      int gx = ((ks * 4 + q) ^ (l15 & 7)) << 3;
      #pragma unroll
      for (int mi = 0; mi < 4; ++mi)
        af[ks][mi] = *(const bfx8*)&a_s[buf][(wm * 64 + mi * 16 + l15) * 64 + gx];
      #pragma unroll
      for (int ni = 0; ni < 2; ++ni)
        bf[ks][ni] = *(const bfx8*)&b_s[buf][(wn * 32 + ni * 16 + l15) * 64 + gx];
    }
    asm volatile("s_waitcnt lgkmcnt(0)" ::: "memory");
    __builtin_amdgcn_s_barrier();       // all waves done reading buf

    if (t + 2 < TPK) {                  // re-stage this buffer with chunk t+2
      size_t co = (size_t)(t + 2) * 16384;
      #pragma unroll
      for (int i = 0; i < 2; ++i) {
        int r0 = wave * 16 + i * 8;
        ASYNC_COPY16(abase + co + (size_t)r0 * 64 + soff, &a_s[buf][r0 * 64]);
        ASYNC_COPY16(bbase + co + (size_t)r0 * 64 + soff, &b_s[buf][r0 * 64]);
      }
    }
    #pragma unroll
    for (int ks = 0; ks < 2; ++ks)
      #pragma unroll
      for (int ni = 0; ni < 2; ++ni)
        #pragma unroll
        for (int mi = 0; mi < 4; ++mi)
          acc[mi][ni] = __builtin_amdgcn_mfma_f32_16x16x32_bf16(af[ks][mi], bf[ks][ni], acc[mi][ni], 0, 0, 0);
  }

  float* dst = f0p + (size_t)kidx * NG * NC0 * HD
             + ((size_t)(g0 + gl) * NC0 + (size_t)mt * 128) * HD + (size_t)nt * 128;
  #pragma unroll
  for (int mi = 0; mi < 4; ++mi)
    #pragma unroll
    for (int ni = 0; ni < 2; ++ni) {
      int c = wm * 64 + mi * 16 + q * 4;
      int h = wn * 32 + ni * 16 + l15;
      #pragma unroll
      for (int r = 0; r < 4; ++r)
        dst[(size_t)(c + r) * HD + h] = acc[mi][ni][r];
    }
}

// ---------------- f0 = f0p0 + f0p1 (in place: f0 == f0p0) ----------------
__global__ __launch_bounds__(256) void k_f0sum(float* __restrict__ f0) {
  size_t i = ((size_t)blockIdx.x * 256 + threadIdx.x) * 4;
  float4 a = *(const float4*)(f0 + i);
  float4 b = *(const float4*)(f0 + (size_t)NG * NC0 * HD + i);
  a.x += b.x; a.y += b.y; a.z += b.z; a.w += b.w;
  *(float4*)(f0 + i) = a;
}

// ---------------- K3: A1 = softmax(f0 @ W1 + b1); W1 staged in LDS ----------------
__global__ __launch_bounds__(256) void k_assign1(
    const float* __restrict__ f0, const float* __restrict__ W1,
    const float* __restrict__ b1, float* __restrict__ A1) {
  __shared__ float w1s[256 * 64];   // 64 KB
  int tid = threadIdx.x;
  #pragma unroll
  for (int i = 0; i < 16; ++i) {
    int off = i * 1024 + tid * 4;
    *(float4*)(w1s + off) = *(const float4*)(W1 + off);
  }
  __syncthreads();
  int lane = tid & 63;
  int rbase = blockIdx.x * 32 + (tid >> 6) * 8;
  float bias = b1[lane];
  for (int rr = 0; rr < 8; ++rr) {
    int row = rbase + rr;
    const float* fr = f0 + (size_t)row * 256;
    float acc = bias;
    for (int k = 0; k < 256; k += 4) {
      float4 fv = *(const float4*)(fr + k);
      acc += fv.x * w1s[(k    ) * 64 + lane];
      acc += fv.y * w1s[(k + 1) * 64 + lane];
      acc += fv.z * w1s[(k + 2) * 64 + lane];
      acc += fv.w * w1s[(k + 3) * 64 + lane];
    }
    float m = acc;
    #pragma unroll
    for (int off = 1; off < 64; off <<= 1) m = fmaxf(m, __shfl_xor(m, off));
    float e = __expf(acc - m);
    float s = e;
    #pragma unroll
    for (int off = 1; off < 64; off <<= 1) s += __shfl_xor(s, off);
    A1[(size_t)row * 64 + lane] = e / s;
  }
}

// ---------------- K4: f1 = A1^T-weighted pool of f0 ----------------
__global__ __launch_bounds__(1024) void k_pool1(
    const float* __restrict__ A1, const float* __restrict__ f0, float* __restrict__ f1) {
  __shared__ float part[3 * 256 * 16];   // 48 KB
  int b = blockIdx.x >> 2, cg = blockIdx.x & 3;
  int tid = threadIdx.x;
  int c0g = tid >> 8;                    // 0..3
  int h = tid & 255;
  const float* a1p = A1 + (size_t)b * NC0 * NC1 + cg * 16;
  const float* f0p = f0 + (size_t)b * NC0 * HD + h;
  float acc[16];
  #pragma unroll
  for (int j = 0; j < 16; ++j) acc[j] = 0.f;
  for (int c0 = c0g * 64; c0 < c0g * 64 + 64; ++c0) {
    float fv = f0p[(size_t)c0 * 256];
    #pragma unroll
    for (int j = 0; j < 16; ++j) acc[j] += a1p[c0 * 64 + j] * fv;
  }
  if (c0g > 0) {
    float* d = &part[((c0g - 1) * 256 + h) * 16];
    #pragma unroll
    for (int j = 0; j < 16; ++j) d[j] = acc[j];
  }
  __syncthreads();
  if (c0g == 0) {
    #pragma unroll
    for (int g = 0; g < 3; ++g) {
      const float* s = &part[(g * 256 + h) * 16];
      #pragma unroll
      for (int j = 0; j < 16; ++j) acc[j] += s[j];
    }
    float* d = f1 + (size_t)b * 16384 + (size_t)(cg * 16) * 256 + h;
    #pragma unroll
    for (int j = 0; j < 16; ++j) d[(size_t)j * 256] = acc[j];
  }
}

// ---------------- K5a: ot += f1 . Wf slice ----------------
__global__ __launch_bounds__(512) void k_final_partial(
    const float* __restrict__ f1, const float* __restrict__ Wf, float* __restrict__ ot) {
  __shared__ float f1s[32 * 256];   // 32 KB: f1[32 graphs][k-slice]
  int ks = blockIdx.x >> 2;
  int ht = (blockIdx.x >> 1) & 1;
  int bh = blockIdx.x & 1;
  int tid = threadIdx.x;
  #pragma unroll
  for (int i = 0; i < 4; ++i) {
    int idx = i * 512 + tid;          // 2048 float4s = 32 rows x 64
    int bb = idx >> 6, c4 = idx & 63;
    *(float4*)(f1s + bb * 256 + c4 * 4) =
        *(const float4*)(f1 + (size_t)(bh * 32 + bb) * 16384 + (size_t)ks * 256 + c4 * 4);
  }
  __syncthreads();
  int h = ht * 128 + (tid & 127);
  int b0 = (tid >> 7) * 8;            // 8 graphs within the half
  const float* wp = Wf + (size_t)ks * 256 * 256 + h;
  float acc[8];
  #pragma unroll
  for (int j = 0; j < 8; ++j) acc[j] = 0.f;
  for (int k = 0; k < 256; k += 4) {
    float w0 = wp[(size_t)(k    ) * 256];
    float w1 = wp[(size_t)(k + 1) * 256];
    float w2 = wp[(size_t)(k + 2) * 256];
    float w3 = wp[(size_t)(k + 3) * 256];
    #pragma unroll
    for (int j = 0; j < 8; ++j) {
      float4 fv = *(const float4*)(f1s + (b0 + j) * 256 + k);
      acc[j] += fv.x * w0 + fv.y * w1 + fv.z * w2 + fv.w * w3;
    }
  }
  #pragma unroll
  for (int j = 0; j < 8; ++j) atomicAdd(&ot[(bh * 32 + b0 + j) * 256 + h], acc[j]);
}

// ---------------- K5b: out = relu(ot + bf) ----------------
__global__ __launch_bounds__(256) void k_final_out(
    const float* __restrict__ ot, const float* __restrict__ bfv, float* __restrict__ out) {
  int i = blockIdx.x * 256 + threadIdx.x;
  float v = ot[i] + bfv[i & 255];
  out[i] = v > 0.f ? v : 0.f;
}

extern "C" void kernel_launch(void* const* d_in, const int* in_sizes, int n_in,
                              void* d_out, int out_size, void* d_ws, size_t ws_size,
                              hipStream_t stream) {
  const float* x   = (const float*)d_in[0];
  const float* W0  = (const float*)d_in[3];
  const float* b0  = (const float*)d_in[4];
  const float* W1  = (const float*)d_in[5];
  const float* b1  = (const float*)d_in[6];
  const float* Wf  = (const float*)d_in[7];
  const float* bfv = (const float*)d_in[8];
  float* out = (float*)d_out;
  char* ws = (char*)d_ws;

  // layout: f0p 2x16 MB @0 (partial0 doubles as f0); ot @32M; W0F @32M+64K;
  // chunk region @32M+192K: xT (G*2MB) + A0T (G*2MB). f1 aliases xT, A1 aliases A0T.
  float* f0p = (float*)ws;
  float* f0  = f0p;
  float* ot  = (float*)(ws + ((size_t)32 << 20));
  unsigned short* W0F = (unsigned short*)(ws + ((size_t)32 << 20) + 65536);
  size_t chunk_off = ((size_t)32 << 20) + 65536 + 131072;
  size_t per_graph = (size_t)4 * HD * NPG;   // xT(2MB)+A0T(2MB)
  size_t avail = ws_size > chunk_off ? ws_size - chunk_off : 0;
  int G = (int)(avail / per_graph);
  if (G > 64) G = 64;   // G=64: pool0 gets its full 512-block grid (2 blocks/CU)
  if (G < 1) G = 1;
  unsigned short* xT  = (unsigned short*)(ws + chunk_off);
  unsigned short* A0T = xT + (size_t)G * HD * NPG;
  float* f1 = (float*)xT;    // 16 MB, used after k_pool0 (needs G>=8)
  float* A1 = (float*)A0T;   // 4 MB, used after k_pool0

  hipMemsetAsync(ot, 0, 65536, stream);
  k_w0f<<<32, 256, 0, stream>>>(W0, W0F);

  for (int g0 = 0; g0 < NG; g0 += G) {
    int gc = (NG - g0 < G) ? (NG - g0) : G;
    k_assign0<<<gc * 64, 256, 0, stream>>>(x, W0F, b0, A0T, xT, g0);
    k_pool0<<<gc * 4 * KSPLIT, 512, 0, stream>>>(A0T, xT, f0p, g0);
  }
  k_f0sum<<<4096, 256, 0, stream>>>(f0);
  k_assign1<<<512, 256, 0, stream>>>(f0, W1, b1, A1);
  k_pool1<<<256, 1024, 0, stream>>>(A1, f0, f1);
  k_final_partial<<<256, 512, 0, stream>>>(f1, Wf, ot);
  k_final_out<<<64, 256, 0, stream>>>(ot, bfv, out);
}